// Round 10
// baseline (1198.325 us; speedup 1.0000x reference)
//
#include <hip/hip_runtime.h>
#include <hip/hip_bf16.h>

// ValueNet: 7x SAGEConv(mean) + global_add_pool + MLP head.
// N=50000 nodes, E=600000 edges/set, H=128, G=64 graphs.
//
// out_i = mean_j(z_j) + bl + y_i,  z = h@Wl, y = h@Wr (linearity of mean).
// GEMM on MFMA bf16 with split precision (hi+lo planes, 3 MFMAs: hh+hl+lh).
// z,y stored bf16. h stored as hi/lo bf16 planes.
//
// CSR build: two-phase bucketed counting sort.
//   Phase A (k_bucket): edges -> per-(pseudoXCD, dst-range) append buckets
//     (dense 8B writes, ~1x writeback) + per-node counts.
//   Phase B (k_scatter): one WG per bucket, LDS-atomic positions, scatter
//     into the bucket's EXCLUSIVE ~49KB adj range (single-owner writes).
//   Replaces the random 4B global scatter that showed 112MB WRITE_SIZE
//   (15x amplification) and 140us in R9's k_build3.
// CSR scratch aliases zb/yb (dead until first gemm, stream-ordered).

constexpr int N_NODES = 50000;
constexpr int NE      = 600000;
constexpr int H       = 128;
constexpr int NG      = 64;
constexpr int N3      = 3 * N_NODES;   // 150000

constexpr int NB   = (N3 + 1023) >> 10;  // 147 dst-range buckets (1024 keys each)
constexpr int NSUB = 8;                  // pseudo-XCD sub-buckets
constexpr int CAP  = 2048;               // per (sub,bucket) capacity (+13 sigma)

typedef __attribute__((ext_vector_type(8))) short short8;
typedef __attribute__((ext_vector_type(4))) float f32x4;

__device__ __forceinline__ ushort f2bf(float f) {  // RNE float->bf16
    uint x = __float_as_uint(f);
    return (ushort)((x + 0x7FFFu + ((x >> 16) & 1u)) >> 16);
}
__device__ __forceinline__ float bf2f(ushort u) {
    return __uint_as_float(((uint)u) << 16);
}

// ---------------- Phase A: bucketize edges + per-node counts ----------------

__global__ void k_bucket(const int* __restrict__ e0, const int* __restrict__ e1,
                         const int* __restrict__ e2, int* __restrict__ bcnt,
                         int* __restrict__ cnt, int2* __restrict__ bucket) {
    int e = blockIdx.x * blockDim.x + threadIdx.x;
    if (e >= 3 * NE) return;
    int s = e / NE, r = e - s * NE;
    const int* ep = (s == 0 ? e0 : (s == 1 ? e1 : e2));
    int d   = ep[NE + r];
    int src = ep[r];
    int key = s * N_NODES + d;
    atomicAdd(&cnt[key], 1);
    int b   = key >> 10;
    int sub = blockIdx.x & 7;            // pseudo-XCD (round-robin heuristic)
    int slot = atomicAdd(&bcnt[sub * NB + b], 1);
    bucket[(size_t)(sub * NB + b) * CAP + slot] = make_int2(key, src);
}

// ---------------- scan: counts -> exclusive prefix (ptr) ----------------

constexpr int SCAN_B  = 256;
constexpr int SCAN_G3 = (N3 + SCAN_B - 1) / SCAN_B;  // 586

__global__ void k_bsum(const int* __restrict__ cnt, int* __restrict__ bsum) {
    __shared__ int sh[SCAN_B];
    int t = threadIdx.x;
    int i = blockIdx.x * SCAN_B + t;
    sh[t] = (i < N3) ? cnt[i] : 0;
    __syncthreads();
    for (int off = SCAN_B / 2; off > 0; off >>= 1) {
        if (t < off) sh[t] += sh[t + off];
        __syncthreads();
    }
    if (t == 0) bsum[blockIdx.x] = sh[0];
}

__global__ void k_bscan(int* bsum, int* ptr) {  // 1 block, 1024 threads
    __shared__ int sh[1024];
    int t = threadIdx.x;
    int v = (t < SCAN_G3) ? bsum[t] : 0;
    sh[t] = v;
    __syncthreads();
    for (int off = 1; off < 1024; off <<= 1) {
        int u = (t >= off) ? sh[t - off] : 0;
        __syncthreads();
        if (t >= off) sh[t] += u;
        __syncthreads();
    }
    if (t < SCAN_G3) bsum[t] = sh[t] - v;     // exclusive block offsets
    if (t == 0) ptr[N3] = sh[1023];           // total = 3*NE
}

__global__ void k_bwrite(const int* cnt, const int* __restrict__ boff,
                         int* __restrict__ ptr) {
    __shared__ int sh[SCAN_B];
    int t = threadIdx.x;
    int i = blockIdx.x * SCAN_B + t;
    int v = (i < N3) ? cnt[i] : 0;
    sh[t] = v;
    __syncthreads();
    for (int off = 1; off < SCAN_B; off <<= 1) {
        int u = (t >= off) ? sh[t - off] : 0;
        __syncthreads();
        if (t >= off) sh[t] += u;
        __syncthreads();
    }
    if (i < N3) ptr[i] = sh[t] - v + boff[blockIdx.x];
}

// ---------------- Phase B: scatter buckets into adj (exclusive ranges) ----------------

__global__ __launch_bounds__(256) void k_scatter(const int2* __restrict__ bucket,
                                                 const int* __restrict__ bcnt,
                                                 const int* __restrict__ ptr,
                                                 int* __restrict__ adj) {
    int b = blockIdx.x;           // 0..NB-1
    int base = b << 10;
    int nk = N3 - base;
    if (nk > 1024) nk = 1024;
    __shared__ int lfill[1024];
    for (int i = threadIdx.x; i < nk; i += 256) lfill[i] = ptr[base + i];
    __syncthreads();
    for (int sub = 0; sub < NSUB; ++sub) {
        int c = bcnt[sub * NB + b];
        const int2* seg = bucket + (size_t)(sub * NB + b) * CAP;
        for (int i = threadIdx.x; i < c; i += 256) {
            int2 ed = seg[i];
            int pos = atomicAdd(&lfill[ed.x - base], 1);
            adj[pos] = ed.y;
        }
    }
}

// ---------------- split x (fp32) -> hi/lo bf16 planes ----------------

__global__ void k_split(const float* __restrict__ x, ushort* __restrict__ hi,
                        ushort* __restrict__ lo) {
    size_t i = ((size_t)blockIdx.x * 256 + threadIdx.x) * 4;
    if (i >= (size_t)N_NODES * H) return;
    float4 v = *(const float4*)(x + i);
    ushort4 h, l;
    h.x = f2bf(v.x); l.x = f2bf(v.x - bf2f(h.x));
    h.y = f2bf(v.y); l.y = f2bf(v.y - bf2f(h.y));
    h.z = f2bf(v.z); l.z = f2bf(v.z - bf2f(h.z));
    h.w = f2bf(v.w); l.w = f2bf(v.w - bf2f(h.w));
    *(ushort4*)(hi + i) = h;
    *(ushort4*)(lo + i) = l;
}

// ---------------- weight pre-scatter into MFMA fragment order (all 5 convs) ----------------
// B = [Wl | Wr]  (128 k x 256 n). k = q*32 + g*8 + j -> ((q*4+g)*256 + n)*8 + j.

__global__ void k_wsplit5(const float* W0l, const float* W0r, const float* W1l,
                          const float* W1r, const float* W2l, const float* W2r,
                          const float* W3l, const float* W3r, const float* W4l,
                          const float* W4r, ushort* __restrict__ Bpk) {
    int idx = blockIdx.x * 256 + threadIdx.x;  // 0..5*32768-1
    if (idx >= 5 * 32768) return;
    int c = idx >> 15, r = idx & 32767;
    const float* Wl = (c == 0 ? W0l : c == 1 ? W1l : c == 2 ? W2l : c == 3 ? W3l : W4l);
    const float* Wr = (c == 0 ? W0r : c == 1 ? W1r : c == 2 ? W2r : c == 3 ? W3r : W4r);
    int n = r & 255, k = r >> 8;
    float w = (n < H) ? Wl[k * H + n] : Wr[k * H + (n - H)];
    int q = k >> 5, g = (k >> 3) & 3, j = k & 7;
    int off = ((q * 4 + g) * 256 + n) * 8 + j;
    ushort h = f2bf(w);
    ushort* bh = Bpk + (size_t)c * 65536;
    bh[off]         = h;
    bh[32768 + off] = f2bf(w - bf2f(h));
}

// ---------------- MFMA GEMM: (z,y) = (Ahi+Alo) @ (Bhi+Blo) ----------------

__global__ __launch_bounds__(256) void k_gemm_mfma(
    const ushort* __restrict__ Ahi, const ushort* __restrict__ Alo,
    const ushort* __restrict__ Bh, const ushort* __restrict__ Bl,
    ushort* __restrict__ z, ushort* __restrict__ yb) {
    __shared__ ushort Ash[2][64][136];
    int t = threadIdx.x;
    int rowBase = blockIdx.x * 64;
    {
        int plane = t >> 7;
        int row   = (t >> 1) & 63;
        int half  = t & 1;
        const ushort* Ap = plane ? Alo : Ahi;
        int grow = rowBase + row;
        if (grow > N_NODES - 1) grow = N_NODES - 1;
        const int4* src = (const int4*)(Ap + (size_t)grow * H + half * 64);
        int4* dst = (int4*)&Ash[plane][row][half * 64];
#pragma unroll
        for (int i = 0; i < 8; ++i) dst[i] = src[i];
    }
    __syncthreads();

    int wave = t >> 6, lane = t & 63;
    int m16 = lane & 15, q4 = lane >> 4;
    int n0 = wave * 64;

    f32x4 acc[4][4];
#pragma unroll
    for (int r = 0; r < 4; ++r)
#pragma unroll
        for (int c = 0; c < 4; ++c) {
            acc[r][c][0] = 0.f; acc[r][c][1] = 0.f;
            acc[r][c][2] = 0.f; acc[r][c][3] = 0.f;
        }

    for (int q = 0; q < 4; ++q) {
        short8 bh_[4], bl_[4], ah_[4], al_[4];
#pragma unroll
        for (int c = 0; c < 4; ++c) {
            int boff = ((q * 4 + q4) * 256 + n0 + c * 16 + m16) * 8;
            bh_[c] = *(const short8*)(Bh + boff);
            bl_[c] = *(const short8*)(Bl + boff);
        }
#pragma unroll
        for (int r = 0; r < 4; ++r) {
            ah_[r] = *(const short8*)&Ash[0][r * 16 + m16][q * 32 + q4 * 8];
            al_[r] = *(const short8*)&Ash[1][r * 16 + m16][q * 32 + q4 * 8];
        }
#pragma unroll
        for (int r = 0; r < 4; ++r)
#pragma unroll
            for (int c = 0; c < 4; ++c) {
                acc[r][c] = __builtin_amdgcn_mfma_f32_16x16x32_bf16(
                    ah_[r], bh_[c], acc[r][c], 0, 0, 0);
                acc[r][c] = __builtin_amdgcn_mfma_f32_16x16x32_bf16(
                    ah_[r], bl_[c], acc[r][c], 0, 0, 0);
                acc[r][c] = __builtin_amdgcn_mfma_f32_16x16x32_bf16(
                    al_[r], bh_[c], acc[r][c], 0, 0, 0);
            }
    }

    // C/D layout: col=lane&15, row=(lane>>4)*4+reg (m89-verified)
#pragma unroll
    for (int r = 0; r < 4; ++r)
#pragma unroll
        for (int c = 0; c < 4; ++c) {
            int col = n0 + c * 16 + m16;
            ushort* op = (col < H) ? (z + col) : (yb + (col - H));
#pragma unroll
            for (int j = 0; j < 4; ++j) {
                int gr = rowBase + r * 16 + q4 * 4 + j;
                if (gr < N_NODES) op[(size_t)gr * H] = f2bf(acc[r][c][j]);
            }
        }
}

// ---------------- gather + epilogue (R6-PROVEN version, frozen) ----------------
// One 32-lane half-wave per node; ushort4 (8B)/lane covers the 256B bf16 row.
// Neighbor idx preloaded 32-wide, broadcast via shfl(width 32); 8-wide ILP.

__global__ __launch_bounds__(256) void k_aggnorm(
    const ushort* __restrict__ z, const ushort* __restrict__ yb,
    const int* __restrict__ ptr, const int* __restrict__ adj,
    const float* __restrict__ bl,
    ushort* __restrict__ hhi, ushort* __restrict__ hlo, int norm) {
    int wid  = (blockIdx.x * blockDim.x + threadIdx.x) >> 6;
    int lane = threadIdx.x & 63;
    int sl   = lane & 31;
    int node = wid * 2 + (lane >> 5);
    if (node >= N_NODES) return;
    int beg = ptr[node], end = ptr[node + 1];
    int deg = end - beg;
    const ushort* zrow = z + sl * 4;
    float a0 = 0.f, a1 = 0.f, a2 = 0.f, a3 = 0.f;
    for (int base = 0; base < deg; base += 32) {
        int m = deg - base;
        if (m > 32) m = 32;
        int idx = (sl < m) ? adj[beg + base + sl] : 0;
        int j = 0;
        for (; j + 8 <= m; j += 8) {
            int n0 = __shfl(idx, j,     32);
            int n1 = __shfl(idx, j + 1, 32);
            int n2 = __shfl(idx, j + 2, 32);
            int n3 = __shfl(idx, j + 3, 32);
            int n4 = __shfl(idx, j + 4, 32);
            int n5 = __shfl(idx, j + 5, 32);
            int n6 = __shfl(idx, j + 6, 32);
            int n7 = __shfl(idx, j + 7, 32);
            ushort4 v0 = *(const ushort4*)(zrow + (size_t)n0 * H);
            ushort4 v1 = *(const ushort4*)(zrow + (size_t)n1 * H);
            ushort4 v2 = *(const ushort4*)(zrow + (size_t)n2 * H);
            ushort4 v3 = *(const ushort4*)(zrow + (size_t)n3 * H);
            ushort4 v4 = *(const ushort4*)(zrow + (size_t)n4 * H);
            ushort4 v5 = *(const ushort4*)(zrow + (size_t)n5 * H);
            ushort4 v6 = *(const ushort4*)(zrow + (size_t)n6 * H);
            ushort4 v7 = *(const ushort4*)(zrow + (size_t)n7 * H);
            a0 += ((bf2f(v0.x) + bf2f(v1.x)) + (bf2f(v2.x) + bf2f(v3.x))) +
                  ((bf2f(v4.x) + bf2f(v5.x)) + (bf2f(v6.x) + bf2f(v7.x)));
            a1 += ((bf2f(v0.y) + bf2f(v1.y)) + (bf2f(v2.y) + bf2f(v3.y))) +
                  ((bf2f(v4.y) + bf2f(v5.y)) + (bf2f(v6.y) + bf2f(v7.y)));
            a2 += ((bf2f(v0.z) + bf2f(v1.z)) + (bf2f(v2.z) + bf2f(v3.z))) +
                  ((bf2f(v4.z) + bf2f(v5.z)) + (bf2f(v6.z) + bf2f(v7.z)));
            a3 += ((bf2f(v0.w) + bf2f(v1.w)) + (bf2f(v2.w) + bf2f(v3.w))) +
                  ((bf2f(v4.w) + bf2f(v5.w)) + (bf2f(v6.w) + bf2f(v7.w)));
        }
        for (; j + 4 <= m; j += 4) {
            int n0 = __shfl(idx, j,     32);
            int n1 = __shfl(idx, j + 1, 32);
            int n2 = __shfl(idx, j + 2, 32);
            int n3 = __shfl(idx, j + 3, 32);
            ushort4 v0 = *(const ushort4*)(zrow + (size_t)n0 * H);
            ushort4 v1 = *(const ushort4*)(zrow + (size_t)n1 * H);
            ushort4 v2 = *(const ushort4*)(zrow + (size_t)n2 * H);
            ushort4 v3 = *(const ushort4*)(zrow + (size_t)n3 * H);
            a0 += (bf2f(v0.x) + bf2f(v1.x)) + (bf2f(v2.x) + bf2f(v3.x));
            a1 += (bf2f(v0.y) + bf2f(v1.y)) + (bf2f(v2.y) + bf2f(v3.y));
            a2 += (bf2f(v0.z) + bf2f(v1.z)) + (bf2f(v2.z) + bf2f(v3.z));
            a3 += (bf2f(v0.w) + bf2f(v1.w)) + (bf2f(v2.w) + bf2f(v3.w));
        }
        for (; j < m; ++j) {
            int n0 = __shfl(idx, j, 32);
            ushort4 v0 = *(const ushort4*)(zrow + (size_t)n0 * H);
            a0 += bf2f(v0.x); a1 += bf2f(v0.y); a2 += bf2f(v0.z); a3 += bf2f(v0.w);
        }
    }
    float inv = 1.0f / (float)(deg > 1 ? deg : 1);
    ushort4 yv = *(const ushort4*)(yb + (size_t)node * H + sl * 4);
    float4 bv = *(const float4*)(bl + sl * 4);
    float v0 = a0 * inv + bv.x + bf2f(yv.x);
    float v1 = a1 * inv + bv.y + bf2f(yv.y);
    float v2 = a2 * inv + bv.z + bf2f(yv.z);
    float v3 = a3 * inv + bv.w + bf2f(yv.w);
    if (norm) {
        float ss = v0 * v0 + v1 * v1 + v2 * v2 + v3 * v3;
#pragma unroll
        for (int m = 1; m < 32; m <<= 1) ss += __shfl_xor(ss, m, 32);
        float n2 = 1.0f / fmaxf(sqrtf(ss), 1e-12f);
        v0 *= n2; v1 *= n2; v2 *= n2; v3 *= n2;
    }
    ushort4 h, l;
    h.x = f2bf(v0); l.x = f2bf(v0 - bf2f(h.x));
    h.y = f2bf(v1); l.y = f2bf(v1 - bf2f(h.y));
    h.z = f2bf(v2); l.z = f2bf(v2 - bf2f(h.z));
    h.w = f2bf(v3); l.w = f2bf(v3 - bf2f(h.w));
    *(ushort4*)(hhi + (size_t)node * H + sl * 4) = h;
    *(ushort4*)(hlo + (size_t)node * H + sl * 4) = l;
}

// ---------------- global add pool (batch sorted), h = hi + lo ----------------

constexpr int POOL_ROWS = 64;

__global__ void k_pool(const ushort* __restrict__ hhi, const ushort* __restrict__ hlo,
                       const int* __restrict__ batch, float* __restrict__ g) {
    int col = threadIdx.x;  // 0..127
    int r0 = blockIdx.x * POOL_ROWS;
    int r1 = r0 + POOL_ROWS;
    if (r1 > N_NODES) r1 = N_NODES;
    if (r0 >= N_NODES) return;
    float acc = 0.f;
    int cur = batch[r0];
    int r = r0;
    for (; r + 4 <= r1; r += 4) {
        float v0 = bf2f(hhi[(size_t)r * H + col])       + bf2f(hlo[(size_t)r * H + col]);
        float v1 = bf2f(hhi[(size_t)(r + 1) * H + col]) + bf2f(hlo[(size_t)(r + 1) * H + col]);
        float v2 = bf2f(hhi[(size_t)(r + 2) * H + col]) + bf2f(hlo[(size_t)(r + 2) * H + col]);
        float v3 = bf2f(hhi[(size_t)(r + 3) * H + col]) + bf2f(hlo[(size_t)(r + 3) * H + col]);
        int b3 = batch[r + 3];
        if (b3 == cur) {
            acc += (v0 + v1) + (v2 + v3);
        } else {
            int b0 = batch[r], b1 = batch[r + 1], b2 = batch[r + 2];
            if (b0 != cur) { atomicAdd(&g[cur * H + col], acc); acc = 0.f; cur = b0; }
            acc += v0;
            if (b1 != cur) { atomicAdd(&g[cur * H + col], acc); acc = 0.f; cur = b1; }
            acc += v1;
            if (b2 != cur) { atomicAdd(&g[cur * H + col], acc); acc = 0.f; cur = b2; }
            acc += v2;
            if (b3 != cur) { atomicAdd(&g[cur * H + col], acc); acc = 0.f; cur = b3; }
            acc += v3;
        }
    }
    for (; r < r1; ++r) {
        int b = batch[r];
        if (b != cur) { atomicAdd(&g[cur * H + col], acc); acc = 0.f; cur = b; }
        acc += bf2f(hhi[(size_t)r * H + col]) + bf2f(hlo[(size_t)r * H + col]);
    }
    atomicAdd(&g[cur * H + col], acc);
}

// ---------------- MLP head ----------------

__global__ void k_mlp(const float* __restrict__ g, const float* __restrict__ W0,
                      const float* __restrict__ b0, const float* __restrict__ W1,
                      const float* __restrict__ b1, const float* __restrict__ Wh,
                      const float* __restrict__ bh, float* __restrict__ out) {
    int gi = blockIdx.x;
    int t  = threadIdx.x;  // 0..127
    __shared__ float buf0[H];
    __shared__ float buf1[H];
    __shared__ float red[2];

    float acc = b0[t];
    for (int k = 0; k < H; ++k) acc += g[gi * H + k] * W0[k * H + t];
    buf0[t] = fmaxf(acc, 0.f);
    __syncthreads();

    acc = b1[t];
    for (int k = 0; k < H; ++k) acc += buf0[k] * W1[k * H + t];
    buf1[t] = fmaxf(acc, 0.f);
    __syncthreads();

    float p = buf1[t] * Wh[t];
    for (int m = 1; m < 64; m <<= 1) p += __shfl_xor(p, m, 64);
    if ((t & 63) == 0) red[t >> 6] = p;
    __syncthreads();
    if (t == 0) out[gi] = red[0] + red[1] + bh[0];
}

// ---------------- driver ----------------

extern "C" void kernel_launch(void* const* d_in, const int* in_sizes, int n_in,
                              void* d_out, int out_size, void* d_ws, size_t ws_size,
                              hipStream_t stream) {
    const float* x     = (const float*)d_in[0];
    const int*   eic   = (const int*)d_in[1];
    const int*   eid   = (const int*)d_in[2];
    const int*   eit   = (const int*)d_in[3];
    const int*   batch = (const int*)d_in[4];
    const float* cW[5][3];
    for (int c = 0; c < 5; ++c) {
        cW[c][0] = (const float*)d_in[5 + c * 3 + 0];  // Wl
        cW[c][1] = (const float*)d_in[5 + c * 3 + 1];  // bl
        cW[c][2] = (const float*)d_in[5 + c * 3 + 2];  // Wr
    }
    const float* l0_W = (const float*)d_in[20];
    const float* l0_b = (const float*)d_in[21];
    const float* l1_W = (const float*)d_in[22];
    const float* l1_b = (const float*)d_in[23];
    const float* hd_W = (const float*)d_in[24];
    const float* hd_b = (const float*)d_in[25];
    float* outp = (float*)d_out;

    const size_t NH = (size_t)N_NODES * H;
    ushort* Ahi = (ushort*)d_ws;
    ushort* Alo = Ahi + NH;
    ushort* zb  = Alo + NH;
    ushort* yb  = zb + NH;
    ushort* Bpk = yb + NH;                     // 5 convs x 2 planes x 32768
    float*  gbuf = (float*)(Bpk + 5 * 2 * 32768);
    int* ptr_all = (int*)(gbuf + (size_t)NG * H);  // N3+1 ints (persistent)
    int* adj_all = ptr_all + (N3 + 1);             // 3*NE ints (persistent)
    // CSR-build scratch inside zb+yb (dead until first gemm, stream-ordered):
    //   cnt[N3] | bcnt[NSUB*NB] | bsum[SCAN_G3] | pad | bucket[NSUB*NB*CAP int2]
    int*  cnt    = (int*)zb;
    int*  bcnt   = cnt + N3;
    int*  bsum   = bcnt + NSUB * NB;
    int2* bucket = (int2*)(bsum + SCAN_G3 + 2);    // 8B-aligned (even int offset)
    // total: 0.61MB + 19.27MB = 19.9MB < zb+yb (25.6MB)

    dim3 b256(256);
    dim3 gE3((3 * NE + 255) / 256);

    // weight pre-scatter + x split
    k_wsplit5<<<dim3(640), b256, 0, stream>>>(cW[0][0], cW[0][2], cW[1][0], cW[1][2],
                                              cW[2][0], cW[2][2], cW[3][0], cW[3][2],
                                              cW[4][0], cW[4][2], Bpk);
    k_split<<<dim3((int)(NH / 1024)), b256, 0, stream>>>(x, Ahi, Alo);

    // CSR build: bucketize+count -> scan -> scatter
    hipMemsetAsync(cnt, 0, (N3 + NSUB * NB) * sizeof(int), stream);  // cnt + bcnt
    k_bucket<<<gE3, b256, 0, stream>>>(eic, eid, eit, bcnt, cnt, bucket);
    k_bsum<<<dim3(SCAN_G3), b256, 0, stream>>>(cnt, bsum);
    k_bscan<<<dim3(1), dim3(1024), 0, stream>>>(bsum, ptr_all);
    k_bwrite<<<dim3(SCAN_G3), b256, 0, stream>>>(cnt, bsum, ptr_all);
    k_scatter<<<dim3(NB), b256, 0, stream>>>(bucket, bcnt, ptr_all, adj_all);

    const int L_set[7]  = {1, 0, 0, 2, 1, 0, 0};
    const int L_conv[7] = {0, 1, 1, 2, 3, 4, 4};
    const int L_norm[7] = {1, 1, 1, 0, 1, 1, 1};

    int nWaves = (N_NODES + 1) / 2;          // 2 nodes per wave (R6-proven)
    dim3 gAgg((nWaves + 3) / 4);             // 4 waves/block
    dim3 gGemm((N_NODES + 63) / 64);         // 782

    for (int L = 0; L < 7; ++L) {
        int s = L_set[L], c = L_conv[L];
        const ushort* Bh = Bpk + (size_t)c * 65536;
        const ushort* Bl = Bh + 32768;
        k_gemm_mfma<<<gGemm, b256, 0, stream>>>(Ahi, Alo, Bh, Bl, zb, yb);
        k_aggnorm<<<gAgg, b256, 0, stream>>>(zb, yb, ptr_all + s * N_NODES, adj_all,
                                             cW[c][1], Ahi, Alo, L_norm[L]);
    }

    hipMemsetAsync(gbuf, 0, (size_t)NG * H * sizeof(float), stream);
    k_pool<<<dim3((N_NODES + POOL_ROWS - 1) / POOL_ROWS), dim3(H), 0, stream>>>(
        Ahi, Alo, batch, gbuf);
    k_mlp<<<dim3(NG), dim3(H), 0, stream>>>(gbuf, l0_W, l0_b, l1_W, l1_b, hd_W, hd_b,
                                            outp);
}

// Round 11
// 603.365 us; speedup vs baseline: 1.9861x; 1.9861x over previous
//
#include <hip/hip_runtime.h>
#include <hip/hip_bf16.h>

// ValueNet: 7x SAGEConv(mean) + global_add_pool + MLP head.
// N=50000 nodes, E=600000 edges/set, H=128, G=64 graphs.
//
// out_i = mean_j(z_j) + bl + y_i,  z = h@Wl, y = h@Wr (linearity of mean).
// GEMM on MFMA bf16 with split precision (hi+lo planes, 3 MFMAs: hh+hl+lh).
// z,y stored bf16. h stored as hi/lo bf16 planes.
//
// CSR build (R11): LDS-staged bucket sort.
//   k_bucketize: per-block LDS histogram over 147 dst-range buckets, one
//     global reserve atomic per (block,bucket), LDS scatter in bucket order,
//     DENSE run-ordered copyout to the bucket arena (run ~112B contiguous).
//     R10's failure (global 8B appends, 98MB writeback, 686us) is fixed by
//     staging in LDS so global writes are sequential within each run.
//   k_scatter2: one WG per bucket, LDS-atomic positions, writes confined to
//     an exclusive ~49KB adj range (full-line writebacks).
// Scratch aliases zb/yb (dead until first gemm, stream-ordered; R9-proven).

constexpr int N_NODES = 50000;
constexpr int NE      = 600000;
constexpr int H       = 128;
constexpr int NG      = 64;
constexpr int N3      = 3 * N_NODES;            // 150000

constexpr int NB   = (N3 + 1023) >> 10;          // 147 buckets (1024 keys each)
constexpr int EPB  = 2048;                       // edges per block (phase A)
constexpr int BPS  = (NE + EPB - 1) / EPB;       // 293 blocks per edge set
constexpr int CAP2 = 14336;                      // bucket capacity (exp 12288, +18 sigma)

typedef __attribute__((ext_vector_type(8))) short short8;
typedef __attribute__((ext_vector_type(4))) float f32x4;

__device__ __forceinline__ ushort f2bf(float f) {  // RNE float->bf16
    uint x = __float_as_uint(f);
    return (ushort)((x + 0x7FFFu + ((x >> 16) & 1u)) >> 16);
}
__device__ __forceinline__ float bf2f(ushort u) {
    return __uint_as_float(((uint)u) << 16);
}

// ---------------- Phase A: LDS-staged bucketize + per-node counts ----------------

__global__ __launch_bounds__(256) void k_bucketize(
    const int* __restrict__ e0, const int* __restrict__ e1,
    const int* __restrict__ e2, int* __restrict__ cnt,
    int* __restrict__ gcnt, int2* __restrict__ bucket) {
    __shared__ int hist[NB];
    __shared__ int basearr[NB];
    __shared__ int cur[NB];
    __shared__ int gposs[NB];
    __shared__ int2 stage[EPB];
    __shared__ int dstoff[EPB];

    int t = threadIdx.x;
    int s = blockIdx.x / BPS;
    int w = blockIdx.x - s * BPS;
    const int* ep = (s == 0 ? e0 : (s == 1 ? e1 : e2));
    int eBase = w * EPB;
    int m = NE - eBase;
    if (m > EPB) m = EPB;

    for (int i = t; i < NB; i += 256) hist[i] = 0;
    __syncthreads();

    // pass 1: read edges into regs, LDS histogram + global per-node count
    int myk[EPB / 256], mys[EPB / 256];
#pragma unroll
    for (int k = 0; k < EPB / 256; ++k) {
        int i = t + 256 * k;
        if (i < m) {
            int d   = ep[NE + eBase + i];
            int src = ep[eBase + i];
            int key = s * N_NODES + d;
            myk[k] = key; mys[k] = src;
            atomicAdd(&hist[key >> 10], 1);
            atomicAdd(&cnt[key], 1);
        } else {
            myk[k] = -1;
        }
    }
    __syncthreads();

    if (t == 0) {  // serial scan over 147 entries (cheap)
        int run = 0;
        for (int b = 0; b < NB; ++b) { basearr[b] = run; run += hist[b]; }
    }
    __syncthreads();

    if (t < NB) {  // reserve arena space: ONE atomic per (block,bucket)
        gposs[t] = hist[t] ? atomicAdd(&gcnt[t], hist[t]) : 0;
        cur[t] = 0;
    }
    __syncthreads();

    // pass 2: scatter into LDS stage in bucket order; record dense dst offsets
#pragma unroll
    for (int k = 0; k < EPB / 256; ++k) {
        if (myk[k] >= 0) {
            int b  = myk[k] >> 10;
            int sl = atomicAdd(&cur[b], 1);
            int p  = basearr[b] + sl;
            stage[p]  = make_int2(myk[k], mys[k]);
            dstoff[p] = b * CAP2 + gposs[b] + sl;
        }
    }
    __syncthreads();

    // copyout: consecutive stage slots within a run -> consecutive global addrs
    for (int i = t; i < m; i += 256) bucket[dstoff[i]] = stage[i];
}

// ---------------- scan: counts -> exclusive prefix (ptr) ----------------

constexpr int SCAN_B  = 256;
constexpr int SCAN_G3 = (N3 + SCAN_B - 1) / SCAN_B;  // 586

__global__ void k_bsum(const int* __restrict__ cnt, int* __restrict__ bsum) {
    __shared__ int sh[SCAN_B];
    int t = threadIdx.x;
    int i = blockIdx.x * SCAN_B + t;
    sh[t] = (i < N3) ? cnt[i] : 0;
    __syncthreads();
    for (int off = SCAN_B / 2; off > 0; off >>= 1) {
        if (t < off) sh[t] += sh[t + off];
        __syncthreads();
    }
    if (t == 0) bsum[blockIdx.x] = sh[0];
}

__global__ void k_bscan(int* bsum, int* ptr) {  // 1 block, 1024 threads
    __shared__ int sh[1024];
    int t = threadIdx.x;
    int v = (t < SCAN_G3) ? bsum[t] : 0;
    sh[t] = v;
    __syncthreads();
    for (int off = 1; off < 1024; off <<= 1) {
        int u = (t >= off) ? sh[t - off] : 0;
        __syncthreads();
        if (t >= off) sh[t] += u;
        __syncthreads();
    }
    if (t < SCAN_G3) bsum[t] = sh[t] - v;     // exclusive block offsets
    if (t == 0) ptr[N3] = sh[1023];           // total = 3*NE
}

__global__ void k_bwrite(const int* cnt, const int* __restrict__ boff,
                         int* __restrict__ ptr) {
    __shared__ int sh[SCAN_B];
    int t = threadIdx.x;
    int i = blockIdx.x * SCAN_B + t;
    int v = (i < N3) ? cnt[i] : 0;
    sh[t] = v;
    __syncthreads();
    for (int off = 1; off < SCAN_B; off <<= 1) {
        int u = (t >= off) ? sh[t - off] : 0;
        __syncthreads();
        if (t >= off) sh[t] += u;
        __syncthreads();
    }
    if (i < N3) ptr[i] = sh[t] - v + boff[blockIdx.x];
}

// ---------------- Phase B: scatter buckets into adj (exclusive ranges) ----------------

__global__ __launch_bounds__(256) void k_scatter2(const int2* __restrict__ bucket,
                                                  const int* __restrict__ gcnt,
                                                  const int* __restrict__ ptr,
                                                  int* __restrict__ adj) {
    int b = blockIdx.x;           // 0..NB-1
    int base = b << 10;
    int nk = N3 - base;
    if (nk > 1024) nk = 1024;
    __shared__ int lfill[1024];
    for (int i = threadIdx.x; i < nk; i += 256) lfill[i] = ptr[base + i];
    __syncthreads();
    int c = gcnt[b];
    const int2* seg = bucket + (size_t)b * CAP2;
    for (int i = threadIdx.x; i < c; i += 256) {
        int2 ed = seg[i];
        int pos = atomicAdd(&lfill[ed.x - base], 1);
        adj[pos] = ed.y;
    }
}

// ---------------- split x (fp32) -> hi/lo bf16 planes ----------------

__global__ void k_split(const float* __restrict__ x, ushort* __restrict__ hi,
                        ushort* __restrict__ lo) {
    size_t i = ((size_t)blockIdx.x * 256 + threadIdx.x) * 4;
    if (i >= (size_t)N_NODES * H) return;
    float4 v = *(const float4*)(x + i);
    ushort4 h, l;
    h.x = f2bf(v.x); l.x = f2bf(v.x - bf2f(h.x));
    h.y = f2bf(v.y); l.y = f2bf(v.y - bf2f(h.y));
    h.z = f2bf(v.z); l.z = f2bf(v.z - bf2f(h.z));
    h.w = f2bf(v.w); l.w = f2bf(v.w - bf2f(h.w));
    *(ushort4*)(hi + i) = h;
    *(ushort4*)(lo + i) = l;
}

// ---------------- weight pre-scatter into MFMA fragment order (all 5 convs) ----------------
// B = [Wl | Wr]  (128 k x 256 n). k = q*32 + g*8 + j -> ((q*4+g)*256 + n)*8 + j.

__global__ void k_wsplit5(const float* W0l, const float* W0r, const float* W1l,
                          const float* W1r, const float* W2l, const float* W2r,
                          const float* W3l, const float* W3r, const float* W4l,
                          const float* W4r, ushort* __restrict__ Bpk) {
    int idx = blockIdx.x * 256 + threadIdx.x;  // 0..5*32768-1
    if (idx >= 5 * 32768) return;
    int c = idx >> 15, r = idx & 32767;
    const float* Wl = (c == 0 ? W0l : c == 1 ? W1l : c == 2 ? W2l : c == 3 ? W3l : W4l);
    const float* Wr = (c == 0 ? W0r : c == 1 ? W1r : c == 2 ? W2r : c == 3 ? W3r : W4r);
    int n = r & 255, k = r >> 8;
    float w = (n < H) ? Wl[k * H + n] : Wr[k * H + (n - H)];
    int q = k >> 5, g = (k >> 3) & 3, j = k & 7;
    int off = ((q * 4 + g) * 256 + n) * 8 + j;
    ushort h = f2bf(w);
    ushort* bh = Bpk + (size_t)c * 65536;
    bh[off]         = h;
    bh[32768 + off] = f2bf(w - bf2f(h));
}

// ---------------- MFMA GEMM: (z,y) = (Ahi+Alo) @ (Bhi+Blo) ----------------

__global__ __launch_bounds__(256) void k_gemm_mfma(
    const ushort* __restrict__ Ahi, const ushort* __restrict__ Alo,
    const ushort* __restrict__ Bh, const ushort* __restrict__ Bl,
    ushort* __restrict__ z, ushort* __restrict__ yb) {
    __shared__ ushort Ash[2][64][136];
    int t = threadIdx.x;
    int rowBase = blockIdx.x * 64;
    {
        int plane = t >> 7;
        int row   = (t >> 1) & 63;
        int half  = t & 1;
        const ushort* Ap = plane ? Alo : Ahi;
        int grow = rowBase + row;
        if (grow > N_NODES - 1) grow = N_NODES - 1;
        const int4* src = (const int4*)(Ap + (size_t)grow * H + half * 64);
        int4* dst = (int4*)&Ash[plane][row][half * 64];
#pragma unroll
        for (int i = 0; i < 8; ++i) dst[i] = src[i];
    }
    __syncthreads();

    int wave = t >> 6, lane = t & 63;
    int m16 = lane & 15, q4 = lane >> 4;
    int n0 = wave * 64;

    f32x4 acc[4][4];
#pragma unroll
    for (int r = 0; r < 4; ++r)
#pragma unroll
        for (int c = 0; c < 4; ++c) {
            acc[r][c][0] = 0.f; acc[r][c][1] = 0.f;
            acc[r][c][2] = 0.f; acc[r][c][3] = 0.f;
        }

    for (int q = 0; q < 4; ++q) {
        short8 bh_[4], bl_[4], ah_[4], al_[4];
#pragma unroll
        for (int c = 0; c < 4; ++c) {
            int boff = ((q * 4 + q4) * 256 + n0 + c * 16 + m16) * 8;
            bh_[c] = *(const short8*)(Bh + boff);
            bl_[c] = *(const short8*)(Bl + boff);
        }
#pragma unroll
        for (int r = 0; r < 4; ++r) {
            ah_[r] = *(const short8*)&Ash[0][r * 16 + m16][q * 32 + q4 * 8];
            al_[r] = *(const short8*)&Ash[1][r * 16 + m16][q * 32 + q4 * 8];
        }
#pragma unroll
        for (int r = 0; r < 4; ++r)
#pragma unroll
            for (int c = 0; c < 4; ++c) {
                acc[r][c] = __builtin_amdgcn_mfma_f32_16x16x32_bf16(
                    ah_[r], bh_[c], acc[r][c], 0, 0, 0);
                acc[r][c] = __builtin_amdgcn_mfma_f32_16x16x32_bf16(
                    ah_[r], bl_[c], acc[r][c], 0, 0, 0);
                acc[r][c] = __builtin_amdgcn_mfma_f32_16x16x32_bf16(
                    al_[r], bh_[c], acc[r][c], 0, 0, 0);
            }
    }

    // C/D layout: col=lane&15, row=(lane>>4)*4+reg (m89-verified)
#pragma unroll
    for (int r = 0; r < 4; ++r)
#pragma unroll
        for (int c = 0; c < 4; ++c) {
            int col = n0 + c * 16 + m16;
            ushort* op = (col < H) ? (z + col) : (yb + (col - H));
#pragma unroll
            for (int j = 0; j < 4; ++j) {
                int gr = rowBase + r * 16 + q4 * 4 + j;
                if (gr < N_NODES) op[(size_t)gr * H] = f2bf(acc[r][c][j]);
            }
        }
}

// ---------------- gather + epilogue (R6-PROVEN version, frozen) ----------------

__global__ __launch_bounds__(256) void k_aggnorm(
    const ushort* __restrict__ z, const ushort* __restrict__ yb,
    const int* __restrict__ ptr, const int* __restrict__ adj,
    const float* __restrict__ bl,
    ushort* __restrict__ hhi, ushort* __restrict__ hlo, int norm) {
    int wid  = (blockIdx.x * blockDim.x + threadIdx.x) >> 6;
    int lane = threadIdx.x & 63;
    int sl   = lane & 31;
    int node = wid * 2 + (lane >> 5);
    if (node >= N_NODES) return;
    int beg = ptr[node], end = ptr[node + 1];
    int deg = end - beg;
    const ushort* zrow = z + sl * 4;
    float a0 = 0.f, a1 = 0.f, a2 = 0.f, a3 = 0.f;
    for (int base = 0; base < deg; base += 32) {
        int m = deg - base;
        if (m > 32) m = 32;
        int idx = (sl < m) ? adj[beg + base + sl] : 0;
        int j = 0;
        for (; j + 8 <= m; j += 8) {
            int n0 = __shfl(idx, j,     32);
            int n1 = __shfl(idx, j + 1, 32);
            int n2 = __shfl(idx, j + 2, 32);
            int n3 = __shfl(idx, j + 3, 32);
            int n4 = __shfl(idx, j + 4, 32);
            int n5 = __shfl(idx, j + 5, 32);
            int n6 = __shfl(idx, j + 6, 32);
            int n7 = __shfl(idx, j + 7, 32);
            ushort4 v0 = *(const ushort4*)(zrow + (size_t)n0 * H);
            ushort4 v1 = *(const ushort4*)(zrow + (size_t)n1 * H);
            ushort4 v2 = *(const ushort4*)(zrow + (size_t)n2 * H);
            ushort4 v3 = *(const ushort4*)(zrow + (size_t)n3 * H);
            ushort4 v4 = *(const ushort4*)(zrow + (size_t)n4 * H);
            ushort4 v5 = *(const ushort4*)(zrow + (size_t)n5 * H);
            ushort4 v6 = *(const ushort4*)(zrow + (size_t)n6 * H);
            ushort4 v7 = *(const ushort4*)(zrow + (size_t)n7 * H);
            a0 += ((bf2f(v0.x) + bf2f(v1.x)) + (bf2f(v2.x) + bf2f(v3.x))) +
                  ((bf2f(v4.x) + bf2f(v5.x)) + (bf2f(v6.x) + bf2f(v7.x)));
            a1 += ((bf2f(v0.y) + bf2f(v1.y)) + (bf2f(v2.y) + bf2f(v3.y))) +
                  ((bf2f(v4.y) + bf2f(v5.y)) + (bf2f(v6.y) + bf2f(v7.y)));
            a2 += ((bf2f(v0.z) + bf2f(v1.z)) + (bf2f(v2.z) + bf2f(v3.z))) +
                  ((bf2f(v4.z) + bf2f(v5.z)) + (bf2f(v6.z) + bf2f(v7.z)));
            a3 += ((bf2f(v0.w) + bf2f(v1.w)) + (bf2f(v2.w) + bf2f(v3.w))) +
                  ((bf2f(v4.w) + bf2f(v5.w)) + (bf2f(v6.w) + bf2f(v7.w)));
        }
        for (; j + 4 <= m; j += 4) {
            int n0 = __shfl(idx, j,     32);
            int n1 = __shfl(idx, j + 1, 32);
            int n2 = __shfl(idx, j + 2, 32);
            int n3 = __shfl(idx, j + 3, 32);
            ushort4 v0 = *(const ushort4*)(zrow + (size_t)n0 * H);
            ushort4 v1 = *(const ushort4*)(zrow + (size_t)n1 * H);
            ushort4 v2 = *(const ushort4*)(zrow + (size_t)n2 * H);
            ushort4 v3 = *(const ushort4*)(zrow + (size_t)n3 * H);
            a0 += (bf2f(v0.x) + bf2f(v1.x)) + (bf2f(v2.x) + bf2f(v3.x));
            a1 += (bf2f(v0.y) + bf2f(v1.y)) + (bf2f(v2.y) + bf2f(v3.y));
            a2 += (bf2f(v0.z) + bf2f(v1.z)) + (bf2f(v2.z) + bf2f(v3.z));
            a3 += (bf2f(v0.w) + bf2f(v1.w)) + (bf2f(v2.w) + bf2f(v3.w));
        }
        for (; j < m; ++j) {
            int n0 = __shfl(idx, j, 32);
            ushort4 v0 = *(const ushort4*)(zrow + (size_t)n0 * H);
            a0 += bf2f(v0.x); a1 += bf2f(v0.y); a2 += bf2f(v0.z); a3 += bf2f(v0.w);
        }
    }
    float inv = 1.0f / (float)(deg > 1 ? deg : 1);
    ushort4 yv = *(const ushort4*)(yb + (size_t)node * H + sl * 4);
    float4 bv = *(const float4*)(bl + sl * 4);
    float v0 = a0 * inv + bv.x + bf2f(yv.x);
    float v1 = a1 * inv + bv.y + bf2f(yv.y);
    float v2 = a2 * inv + bv.z + bf2f(yv.z);
    float v3 = a3 * inv + bv.w + bf2f(yv.w);
    if (norm) {
        float ss = v0 * v0 + v1 * v1 + v2 * v2 + v3 * v3;
#pragma unroll
        for (int m = 1; m < 32; m <<= 1) ss += __shfl_xor(ss, m, 32);
        float n2 = 1.0f / fmaxf(sqrtf(ss), 1e-12f);
        v0 *= n2; v1 *= n2; v2 *= n2; v3 *= n2;
    }
    ushort4 h, l;
    h.x = f2bf(v0); l.x = f2bf(v0 - bf2f(h.x));
    h.y = f2bf(v1); l.y = f2bf(v1 - bf2f(h.y));
    h.z = f2bf(v2); l.z = f2bf(v2 - bf2f(h.z));
    h.w = f2bf(v3); l.w = f2bf(v3 - bf2f(h.w));
    *(ushort4*)(hhi + (size_t)node * H + sl * 4) = h;
    *(ushort4*)(hlo + (size_t)node * H + sl * 4) = l;
}

// ---------------- global add pool (batch sorted), h = hi + lo ----------------

constexpr int POOL_ROWS = 64;

__global__ void k_pool(const ushort* __restrict__ hhi, const ushort* __restrict__ hlo,
                       const int* __restrict__ batch, float* __restrict__ g) {
    int col = threadIdx.x;  // 0..127
    int r0 = blockIdx.x * POOL_ROWS;
    int r1 = r0 + POOL_ROWS;
    if (r1 > N_NODES) r1 = N_NODES;
    if (r0 >= N_NODES) return;
    float acc = 0.f;
    int cur = batch[r0];
    int r = r0;
    for (; r + 4 <= r1; r += 4) {
        float v0 = bf2f(hhi[(size_t)r * H + col])       + bf2f(hlo[(size_t)r * H + col]);
        float v1 = bf2f(hhi[(size_t)(r + 1) * H + col]) + bf2f(hlo[(size_t)(r + 1) * H + col]);
        float v2 = bf2f(hhi[(size_t)(r + 2) * H + col]) + bf2f(hlo[(size_t)(r + 2) * H + col]);
        float v3 = bf2f(hhi[(size_t)(r + 3) * H + col]) + bf2f(hlo[(size_t)(r + 3) * H + col]);
        int b3 = batch[r + 3];
        if (b3 == cur) {
            acc += (v0 + v1) + (v2 + v3);
        } else {
            int b0 = batch[r], b1 = batch[r + 1], b2 = batch[r + 2];
            if (b0 != cur) { atomicAdd(&g[cur * H + col], acc); acc = 0.f; cur = b0; }
            acc += v0;
            if (b1 != cur) { atomicAdd(&g[cur * H + col], acc); acc = 0.f; cur = b1; }
            acc += v1;
            if (b2 != cur) { atomicAdd(&g[cur * H + col], acc); acc = 0.f; cur = b2; }
            acc += v2;
            if (b3 != cur) { atomicAdd(&g[cur * H + col], acc); acc = 0.f; cur = b3; }
            acc += v3;
        }
    }
    for (; r < r1; ++r) {
        int b = batch[r];
        if (b != cur) { atomicAdd(&g[cur * H + col], acc); acc = 0.f; cur = b; }
        acc += bf2f(hhi[(size_t)r * H + col]) + bf2f(hlo[(size_t)r * H + col]);
    }
    atomicAdd(&g[cur * H + col], acc);
}

// ---------------- MLP head ----------------

__global__ void k_mlp(const float* __restrict__ g, const float* __restrict__ W0,
                      const float* __restrict__ b0, const float* __restrict__ W1,
                      const float* __restrict__ b1, const float* __restrict__ Wh,
                      const float* __restrict__ bh, float* __restrict__ out) {
    int gi = blockIdx.x;
    int t  = threadIdx.x;  // 0..127
    __shared__ float buf0[H];
    __shared__ float buf1[H];
    __shared__ float red[2];

    float acc = b0[t];
    for (int k = 0; k < H; ++k) acc += g[gi * H + k] * W0[k * H + t];
    buf0[t] = fmaxf(acc, 0.f);
    __syncthreads();

    acc = b1[t];
    for (int k = 0; k < H; ++k) acc += buf0[k] * W1[k * H + t];
    buf1[t] = fmaxf(acc, 0.f);
    __syncthreads();

    float p = buf1[t] * Wh[t];
    for (int m = 1; m < 64; m <<= 1) p += __shfl_xor(p, m, 64);
    if ((t & 63) == 0) red[t >> 6] = p;
    __syncthreads();
    if (t == 0) out[gi] = red[0] + red[1] + bh[0];
}

// ---------------- driver ----------------

extern "C" void kernel_launch(void* const* d_in, const int* in_sizes, int n_in,
                              void* d_out, int out_size, void* d_ws, size_t ws_size,
                              hipStream_t stream) {
    const float* x     = (const float*)d_in[0];
    const int*   eic   = (const int*)d_in[1];
    const int*   eid   = (const int*)d_in[2];
    const int*   eit   = (const int*)d_in[3];
    const int*   batch = (const int*)d_in[4];
    const float* cW[5][3];
    for (int c = 0; c < 5; ++c) {
        cW[c][0] = (const float*)d_in[5 + c * 3 + 0];  // Wl
        cW[c][1] = (const float*)d_in[5 + c * 3 + 1];  // bl
        cW[c][2] = (const float*)d_in[5 + c * 3 + 2];  // Wr
    }
    const float* l0_W = (const float*)d_in[20];
    const float* l0_b = (const float*)d_in[21];
    const float* l1_W = (const float*)d_in[22];
    const float* l1_b = (const float*)d_in[23];
    const float* hd_W = (const float*)d_in[24];
    const float* hd_b = (const float*)d_in[25];
    float* outp = (float*)d_out;

    const size_t NH = (size_t)N_NODES * H;
    ushort* Ahi = (ushort*)d_ws;
    ushort* Alo = Ahi + NH;
    ushort* zb  = Alo + NH;
    ushort* yb  = zb + NH;
    ushort* Bpk = yb + NH;                     // 5 convs x 2 planes x 32768
    float*  gbuf = (float*)(Bpk + 5 * 2 * 32768);
    int* ptr_all = (int*)(gbuf + (size_t)NG * H);  // N3+1 ints (persistent)
    int* adj_all = ptr_all + (N3 + 1);             // 3*NE ints (persistent)
    // CSR-build scratch inside zb+yb (dead until first gemm, stream-ordered):
    //   cnt[N3] | gcnt[NB] | bsum[SCAN_G3] | pad | bucket[NB*CAP2 int2]
    int*  cnt    = (int*)zb;
    int*  gcnt   = cnt + N3;
    int*  bsum   = gcnt + NB;
    int2* bucket = (int2*)(bsum + SCAN_G3 + 1);    // even int offset -> 8B aligned
    // total: 0.60MB + 16.9MB = 17.5MB < zb+yb (25.6MB)

    dim3 b256(256);

    // weight pre-scatter + x split
    k_wsplit5<<<dim3(640), b256, 0, stream>>>(cW[0][0], cW[0][2], cW[1][0], cW[1][2],
                                              cW[2][0], cW[2][2], cW[3][0], cW[3][2],
                                              cW[4][0], cW[4][2], Bpk);
    k_split<<<dim3((int)(NH / 1024)), b256, 0, stream>>>(x, Ahi, Alo);

    // CSR build: LDS-staged bucketize -> scan -> per-bucket scatter
    hipMemsetAsync(cnt, 0, (N3 + NB) * sizeof(int), stream);  // cnt + gcnt
    k_bucketize<<<dim3(3 * BPS), b256, 0, stream>>>(eic, eid, eit, cnt, gcnt, bucket);
    k_bsum<<<dim3(SCAN_G3), b256, 0, stream>>>(cnt, bsum);
    k_bscan<<<dim3(1), dim3(1024), 0, stream>>>(bsum, ptr_all);
    k_bwrite<<<dim3(SCAN_G3), b256, 0, stream>>>(cnt, bsum, ptr_all);
    k_scatter2<<<dim3(NB), b256, 0, stream>>>(bucket, gcnt, ptr_all, adj_all);

    const int L_set[7]  = {1, 0, 0, 2, 1, 0, 0};
    const int L_conv[7] = {0, 1, 1, 2, 3, 4, 4};
    const int L_norm[7] = {1, 1, 1, 0, 1, 1, 1};

    int nWaves = (N_NODES + 1) / 2;          // 2 nodes per wave (R6-proven)
    dim3 gAgg((nWaves + 3) / 4);             // 4 waves/block
    dim3 gGemm((N_NODES + 63) / 64);         // 782

    for (int L = 0; L < 7; ++L) {
        int s = L_set[L], c = L_conv[L];
        const ushort* Bh = Bpk + (size_t)c * 65536;
        const ushort* Bl = Bh + 32768;
        k_gemm_mfma<<<gGemm, b256, 0, stream>>>(Ahi, Alo, Bh, Bl, zb, yb);
        k_aggnorm<<<gAgg, b256, 0, stream>>>(zb, yb, ptr_all + s * N_NODES, adj_all,
                                             cW[c][1], Ahi, Alo, L_norm[L]);
    }

    hipMemsetAsync(gbuf, 0, (size_t)NG * H * sizeof(float), stream);
    k_pool<<<dim3((N_NODES + POOL_ROWS - 1) / POOL_ROWS), dim3(H), 0, stream>>>(
        Ahi, Alo, batch, gbuf);
    k_mlp<<<dim3(NG), dim3(H), 0, stream>>>(gbuf, l0_W, l0_b, l1_W, l1_b, hd_W, hd_b,
                                            outp);
}

// Round 12
// 551.902 us; speedup vs baseline: 2.1713x; 1.0932x over previous
//
#include <hip/hip_runtime.h>
#include <hip/hip_bf16.h>

// ValueNet: 7x SAGEConv(mean) + global_add_pool + MLP head.
// N=50000 nodes, E=600000 edges/set, H=128, G=64 graphs.
//
// out_i = mean_j(z_j) + bl + y_i,  z = h@Wl, y = h@Wr (linearity of mean).
// GEMM on MFMA bf16 with split precision (hi+lo planes, 3 MFMAs: hh+hl+lh).
// z,y stored bf16. h stored as hi/lo bf16 planes.
//
// CSR build (R12): LDS-staged bucket sort, NO per-key global atomics.
//   k_bucketize: per-block LDS histogram over 147 buckets, 8-slot-PADDED
//     arena reservation (runs 64B-aligned -> no partial/shared lines),
//     sentinel (-1) fill for pad slots, dense run-ordered copyout.
//     R11 evidence: 1.8M random cnt atomics carried ~50MB of HBM writeback.
//   k_btscan: 1-block scan of 147 real bucket totals -> bbase.
//   k_scatter2: per bucket: LDS hist (skip sentinels) + LDS 1024-scan ->
//     writes ptr slice densely + scatters adj into exclusive ~48KB range.
// Scratch aliases zb/yb (dead until first gemm, stream-ordered; R9-proven).

constexpr int N_NODES = 50000;
constexpr int NE      = 600000;
constexpr int H       = 128;
constexpr int NG      = 64;
constexpr int N3      = 3 * N_NODES;            // 150000

constexpr int NB   = (N3 + 1023) >> 10;          // 147 buckets (1024 keys each)
constexpr int EPB  = 2048;                       // edges per block (phase A)
constexpr int BPS  = (NE + EPB - 1) / EPB;       // 293 blocks per edge set
constexpr int CAP2 = 19456;                      // slots/bucket (exp ~15.4k padded; mult of 8)

typedef __attribute__((ext_vector_type(8))) short short8;
typedef __attribute__((ext_vector_type(4))) float f32x4;

__device__ __forceinline__ ushort f2bf(float f) {  // RNE float->bf16
    uint x = __float_as_uint(f);
    return (ushort)((x + 0x7FFFu + ((x >> 16) & 1u)) >> 16);
}
__device__ __forceinline__ float bf2f(ushort u) {
    return __uint_as_float(((uint)u) << 16);
}

// ---------------- Phase A: LDS-staged bucketize (padded, sentinel-filled) ----------------

__global__ __launch_bounds__(256) void k_bucketize(
    const int* __restrict__ e0, const int* __restrict__ e1,
    const int* __restrict__ e2, int* __restrict__ gcnt,
    int* __restrict__ rcnt, int2* __restrict__ bucket) {
    __shared__ int hist[NB];
    __shared__ int basearr[NB];
    __shared__ int cur[NB];
    __shared__ int gposs[NB];
    __shared__ int2 stage[EPB];
    __shared__ int dstoff[EPB];

    int t = threadIdx.x;
    int s = blockIdx.x / BPS;
    int w = blockIdx.x - s * BPS;
    const int* ep = (s == 0 ? e0 : (s == 1 ? e1 : e2));
    int eBase = w * EPB;
    int m = NE - eBase;
    if (m > EPB) m = EPB;

    for (int i = t; i < NB; i += 256) hist[i] = 0;
    __syncthreads();

    // pass 1: read edges into regs, LDS histogram
    int myk[EPB / 256], mys[EPB / 256];
#pragma unroll
    for (int k = 0; k < EPB / 256; ++k) {
        int i = t + 256 * k;
        if (i < m) {
            int d   = ep[NE + eBase + i];
            int src = ep[eBase + i];
            int key = s * N_NODES + d;
            myk[k] = key; mys[k] = src;
            atomicAdd(&hist[key >> 10], 1);
        } else {
            myk[k] = -1;
        }
    }
    __syncthreads();

    if (t == 0) {  // serial scan over 147 entries (cheap)
        int run = 0;
        for (int b = 0; b < NB; ++b) { basearr[b] = run; run += hist[b]; }
    }
    __syncthreads();

    if (t < NB) {  // padded reserve: ONE atomic per (block,bucket); runs 64B-aligned
        int h = hist[t];
        int p = (h + 7) & ~7;
        gposs[t] = p ? atomicAdd(&gcnt[t], p) : 0;
        if (h) atomicAdd(&rcnt[t], h);
        cur[t] = 0;
    }
    __syncthreads();

    // pass 2: scatter into LDS stage in bucket order; record dense dst offsets
#pragma unroll
    for (int k = 0; k < EPB / 256; ++k) {
        if (myk[k] >= 0) {
            int b  = myk[k] >> 10;
            int sl = atomicAdd(&cur[b], 1);
            int p  = basearr[b] + sl;
            stage[p]  = make_int2(myk[k], mys[k]);
            dstoff[p] = b * CAP2 + gposs[b] + sl;
        }
    }
    __syncthreads();

    // copyout: consecutive stage slots within a run -> consecutive global addrs
    for (int i = t; i < m; i += 256) bucket[dstoff[i]] = stage[i];
    // sentinel-fill the pad slots (<=7 per (block,bucket), same lines as runs)
    for (int i = t; i < NB * 8; i += 256) {
        int b = i >> 3, j = i & 7;
        int h = hist[b];
        int p = (h + 7) & ~7;
        if (h + j < p)
            bucket[(size_t)b * CAP2 + gposs[b] + h + j] = make_int2(-1, 0);
    }
}

// ---------------- bucket-total scan (147 values, 1 block) ----------------

__global__ void k_btscan(const int* __restrict__ rcnt, int* __restrict__ bbase,
                         int* __restrict__ ptr) {
    __shared__ int sh[256];
    int t = threadIdx.x;
    int v = (t < NB) ? rcnt[t] : 0;
    sh[t] = v;
    __syncthreads();
    for (int off = 1; off < 256; off <<= 1) {
        int u = (t >= off) ? sh[t - off] : 0;
        __syncthreads();
        if (t >= off) sh[t] += u;
        __syncthreads();
    }
    if (t < NB) bbase[t] = sh[t] - v;   // exclusive prefix of real totals
    if (t == 0) ptr[N3] = 3 * NE;
}

// ---------------- Phase B: per-bucket hist + scan -> ptr slice + adj scatter ----------------

__global__ __launch_bounds__(256) void k_scatter2(const int2* __restrict__ bucket,
                                                  const int* __restrict__ gcnt,
                                                  const int* __restrict__ bbase,
                                                  int* __restrict__ ptr,
                                                  int* __restrict__ adj) {
    int b = blockIdx.x;           // 0..NB-1
    int base = b << 10;
    int nk = N3 - base;
    if (nk > 1024) nk = 1024;
    __shared__ int lh[1024];
    __shared__ int lsum[256];
    __shared__ int lfill[1024];
    int t = threadIdx.x;
    for (int i = t; i < 1024; i += 256) lh[i] = 0;
    __syncthreads();
    int c = gcnt[b];              // padded slot count actually used
    const int2* seg = bucket + (size_t)b * CAP2;
    for (int i = t; i < c; i += 256) {
        int k = seg[i].x;
        if (k >= 0) atomicAdd(&lh[k - base], 1);
    }
    __syncthreads();
    // exclusive 1024-scan: 4 seq per thread + 256 Hillis-Steele
    int v0 = lh[t * 4], v1 = lh[t * 4 + 1], v2 = lh[t * 4 + 2], v3 = lh[t * 4 + 3];
    int ts = v0 + v1 + v2 + v3;
    lsum[t] = ts;
    __syncthreads();
    for (int off = 1; off < 256; off <<= 1) {
        int u = (t >= off) ? lsum[t - off] : 0;
        __syncthreads();
        if (t >= off) lsum[t] += u;
        __syncthreads();
    }
    int ex = lsum[t] - ts + bbase[b];
    int e0 = ex, e1 = ex + v0, e2 = ex + v0 + v1, e3 = ex + v0 + v1 + v2;
    if (t * 4     < nk) { ptr[base + t * 4]     = e0; lfill[t * 4]     = e0; }
    if (t * 4 + 1 < nk) { ptr[base + t * 4 + 1] = e1; lfill[t * 4 + 1] = e1; }
    if (t * 4 + 2 < nk) { ptr[base + t * 4 + 2] = e2; lfill[t * 4 + 2] = e2; }
    if (t * 4 + 3 < nk) { ptr[base + t * 4 + 3] = e3; lfill[t * 4 + 3] = e3; }
    __syncthreads();
    for (int i = t; i < c; i += 256) {
        int2 ed = seg[i];
        if (ed.x >= 0) {
            int pos = atomicAdd(&lfill[ed.x - base], 1);
            adj[pos] = ed.y;
        }
    }
}

// ---------------- split x (fp32) -> hi/lo bf16 planes ----------------

__global__ void k_split(const float* __restrict__ x, ushort* __restrict__ hi,
                        ushort* __restrict__ lo) {
    size_t i = ((size_t)blockIdx.x * 256 + threadIdx.x) * 4;
    if (i >= (size_t)N_NODES * H) return;
    float4 v = *(const float4*)(x + i);
    ushort4 h, l;
    h.x = f2bf(v.x); l.x = f2bf(v.x - bf2f(h.x));
    h.y = f2bf(v.y); l.y = f2bf(v.y - bf2f(h.y));
    h.z = f2bf(v.z); l.z = f2bf(v.z - bf2f(h.z));
    h.w = f2bf(v.w); l.w = f2bf(v.w - bf2f(h.w));
    *(ushort4*)(hi + i) = h;
    *(ushort4*)(lo + i) = l;
}

// ---------------- weight pre-scatter into MFMA fragment order (all 5 convs) ----------------
// B = [Wl | Wr]  (128 k x 256 n). k = q*32 + g*8 + j -> ((q*4+g)*256 + n)*8 + j.

__global__ void k_wsplit5(const float* W0l, const float* W0r, const float* W1l,
                          const float* W1r, const float* W2l, const float* W2r,
                          const float* W3l, const float* W3r, const float* W4l,
                          const float* W4r, ushort* __restrict__ Bpk) {
    int idx = blockIdx.x * 256 + threadIdx.x;  // 0..5*32768-1
    if (idx >= 5 * 32768) return;
    int c = idx >> 15, r = idx & 32767;
    const float* Wl = (c == 0 ? W0l : c == 1 ? W1l : c == 2 ? W2l : c == 3 ? W3l : W4l);
    const float* Wr = (c == 0 ? W0r : c == 1 ? W1r : c == 2 ? W2r : c == 3 ? W3r : W4r);
    int n = r & 255, k = r >> 8;
    float w = (n < H) ? Wl[k * H + n] : Wr[k * H + (n - H)];
    int q = k >> 5, g = (k >> 3) & 3, j = k & 7;
    int off = ((q * 4 + g) * 256 + n) * 8 + j;
    ushort h = f2bf(w);
    ushort* bh = Bpk + (size_t)c * 65536;
    bh[off]         = h;
    bh[32768 + off] = f2bf(w - bf2f(h));
}

// ---------------- MFMA GEMM: (z,y) = (Ahi+Alo) @ (Bhi+Blo) ----------------

__global__ __launch_bounds__(256) void k_gemm_mfma(
    const ushort* __restrict__ Ahi, const ushort* __restrict__ Alo,
    const ushort* __restrict__ Bh, const ushort* __restrict__ Bl,
    ushort* __restrict__ z, ushort* __restrict__ yb) {
    __shared__ ushort Ash[2][64][136];
    int t = threadIdx.x;
    int rowBase = blockIdx.x * 64;
    {
        int plane = t >> 7;
        int row   = (t >> 1) & 63;
        int half  = t & 1;
        const ushort* Ap = plane ? Alo : Ahi;
        int grow = rowBase + row;
        if (grow > N_NODES - 1) grow = N_NODES - 1;
        const int4* src = (const int4*)(Ap + (size_t)grow * H + half * 64);
        int4* dst = (int4*)&Ash[plane][row][half * 64];
#pragma unroll
        for (int i = 0; i < 8; ++i) dst[i] = src[i];
    }
    __syncthreads();

    int wave = t >> 6, lane = t & 63;
    int m16 = lane & 15, q4 = lane >> 4;
    int n0 = wave * 64;

    f32x4 acc[4][4];
#pragma unroll
    for (int r = 0; r < 4; ++r)
#pragma unroll
        for (int c = 0; c < 4; ++c) {
            acc[r][c][0] = 0.f; acc[r][c][1] = 0.f;
            acc[r][c][2] = 0.f; acc[r][c][3] = 0.f;
        }

    for (int q = 0; q < 4; ++q) {
        short8 bh_[4], bl_[4], ah_[4], al_[4];
#pragma unroll
        for (int c = 0; c < 4; ++c) {
            int boff = ((q * 4 + q4) * 256 + n0 + c * 16 + m16) * 8;
            bh_[c] = *(const short8*)(Bh + boff);
            bl_[c] = *(const short8*)(Bl + boff);
        }
#pragma unroll
        for (int r = 0; r < 4; ++r) {
            ah_[r] = *(const short8*)&Ash[0][r * 16 + m16][q * 32 + q4 * 8];
            al_[r] = *(const short8*)&Ash[1][r * 16 + m16][q * 32 + q4 * 8];
        }
#pragma unroll
        for (int r = 0; r < 4; ++r)
#pragma unroll
            for (int c = 0; c < 4; ++c) {
                acc[r][c] = __builtin_amdgcn_mfma_f32_16x16x32_bf16(
                    ah_[r], bh_[c], acc[r][c], 0, 0, 0);
                acc[r][c] = __builtin_amdgcn_mfma_f32_16x16x32_bf16(
                    ah_[r], bl_[c], acc[r][c], 0, 0, 0);
                acc[r][c] = __builtin_amdgcn_mfma_f32_16x16x32_bf16(
                    al_[r], bh_[c], acc[r][c], 0, 0, 0);
            }
    }

    // C/D layout: col=lane&15, row=(lane>>4)*4+reg (m89-verified)
#pragma unroll
    for (int r = 0; r < 4; ++r)
#pragma unroll
        for (int c = 0; c < 4; ++c) {
            int col = n0 + c * 16 + m16;
            ushort* op = (col < H) ? (z + col) : (yb + (col - H));
#pragma unroll
            for (int j = 0; j < 4; ++j) {
                int gr = rowBase + r * 16 + q4 * 4 + j;
                if (gr < N_NODES) op[(size_t)gr * H] = f2bf(acc[r][c][j]);
            }
        }
}

// ---------------- gather + epilogue (R6-PROVEN version, frozen) ----------------

__global__ __launch_bounds__(256) void k_aggnorm(
    const ushort* __restrict__ z, const ushort* __restrict__ yb,
    const int* __restrict__ ptr, const int* __restrict__ adj,
    const float* __restrict__ bl,
    ushort* __restrict__ hhi, ushort* __restrict__ hlo, int norm) {
    int wid  = (blockIdx.x * blockDim.x + threadIdx.x) >> 6;
    int lane = threadIdx.x & 63;
    int sl   = lane & 31;
    int node = wid * 2 + (lane >> 5);
    if (node >= N_NODES) return;
    int beg = ptr[node], end = ptr[node + 1];
    int deg = end - beg;
    const ushort* zrow = z + sl * 4;
    float a0 = 0.f, a1 = 0.f, a2 = 0.f, a3 = 0.f;
    for (int base = 0; base < deg; base += 32) {
        int m = deg - base;
        if (m > 32) m = 32;
        int idx = (sl < m) ? adj[beg + base + sl] : 0;
        int j = 0;
        for (; j + 8 <= m; j += 8) {
            int n0 = __shfl(idx, j,     32);
            int n1 = __shfl(idx, j + 1, 32);
            int n2 = __shfl(idx, j + 2, 32);
            int n3 = __shfl(idx, j + 3, 32);
            int n4 = __shfl(idx, j + 4, 32);
            int n5 = __shfl(idx, j + 5, 32);
            int n6 = __shfl(idx, j + 6, 32);
            int n7 = __shfl(idx, j + 7, 32);
            ushort4 v0 = *(const ushort4*)(zrow + (size_t)n0 * H);
            ushort4 v1 = *(const ushort4*)(zrow + (size_t)n1 * H);
            ushort4 v2 = *(const ushort4*)(zrow + (size_t)n2 * H);
            ushort4 v3 = *(const ushort4*)(zrow + (size_t)n3 * H);
            ushort4 v4 = *(const ushort4*)(zrow + (size_t)n4 * H);
            ushort4 v5 = *(const ushort4*)(zrow + (size_t)n5 * H);
            ushort4 v6 = *(const ushort4*)(zrow + (size_t)n6 * H);
            ushort4 v7 = *(const ushort4*)(zrow + (size_t)n7 * H);
            a0 += ((bf2f(v0.x) + bf2f(v1.x)) + (bf2f(v2.x) + bf2f(v3.x))) +
                  ((bf2f(v4.x) + bf2f(v5.x)) + (bf2f(v6.x) + bf2f(v7.x)));
            a1 += ((bf2f(v0.y) + bf2f(v1.y)) + (bf2f(v2.y) + bf2f(v3.y))) +
                  ((bf2f(v4.y) + bf2f(v5.y)) + (bf2f(v6.y) + bf2f(v7.y)));
            a2 += ((bf2f(v0.z) + bf2f(v1.z)) + (bf2f(v2.z) + bf2f(v3.z))) +
                  ((bf2f(v4.z) + bf2f(v5.z)) + (bf2f(v6.z) + bf2f(v7.z)));
            a3 += ((bf2f(v0.w) + bf2f(v1.w)) + (bf2f(v2.w) + bf2f(v3.w))) +
                  ((bf2f(v4.w) + bf2f(v5.w)) + (bf2f(v6.w) + bf2f(v7.w)));
        }
        for (; j + 4 <= m; j += 4) {
            int n0 = __shfl(idx, j,     32);
            int n1 = __shfl(idx, j + 1, 32);
            int n2 = __shfl(idx, j + 2, 32);
            int n3 = __shfl(idx, j + 3, 32);
            ushort4 v0 = *(const ushort4*)(zrow + (size_t)n0 * H);
            ushort4 v1 = *(const ushort4*)(zrow + (size_t)n1 * H);
            ushort4 v2 = *(const ushort4*)(zrow + (size_t)n2 * H);
            ushort4 v3 = *(const ushort4*)(zrow + (size_t)n3 * H);
            a0 += (bf2f(v0.x) + bf2f(v1.x)) + (bf2f(v2.x) + bf2f(v3.x));
            a1 += (bf2f(v0.y) + bf2f(v1.y)) + (bf2f(v2.y) + bf2f(v3.y));
            a2 += (bf2f(v0.z) + bf2f(v1.z)) + (bf2f(v2.z) + bf2f(v3.z));
            a3 += (bf2f(v0.w) + bf2f(v1.w)) + (bf2f(v2.w) + bf2f(v3.w));
        }
        for (; j < m; ++j) {
            int n0 = __shfl(idx, j, 32);
            ushort4 v0 = *(const ushort4*)(zrow + (size_t)n0 * H);
            a0 += bf2f(v0.x); a1 += bf2f(v0.y); a2 += bf2f(v0.z); a3 += bf2f(v0.w);
        }
    }
    float inv = 1.0f / (float)(deg > 1 ? deg : 1);
    ushort4 yv = *(const ushort4*)(yb + (size_t)node * H + sl * 4);
    float4 bv = *(const float4*)(bl + sl * 4);
    float v0 = a0 * inv + bv.x + bf2f(yv.x);
    float v1 = a1 * inv + bv.y + bf2f(yv.y);
    float v2 = a2 * inv + bv.z + bf2f(yv.z);
    float v3 = a3 * inv + bv.w + bf2f(yv.w);
    if (norm) {
        float ss = v0 * v0 + v1 * v1 + v2 * v2 + v3 * v3;
#pragma unroll
        for (int m = 1; m < 32; m <<= 1) ss += __shfl_xor(ss, m, 32);
        float n2 = 1.0f / fmaxf(sqrtf(ss), 1e-12f);
        v0 *= n2; v1 *= n2; v2 *= n2; v3 *= n2;
    }
    ushort4 h, l;
    h.x = f2bf(v0); l.x = f2bf(v0 - bf2f(h.x));
    h.y = f2bf(v1); l.y = f2bf(v1 - bf2f(h.y));
    h.z = f2bf(v2); l.z = f2bf(v2 - bf2f(h.z));
    h.w = f2bf(v3); l.w = f2bf(v3 - bf2f(h.w));
    *(ushort4*)(hhi + (size_t)node * H + sl * 4) = h;
    *(ushort4*)(hlo + (size_t)node * H + sl * 4) = l;
}

// ---------------- global add pool (batch sorted), h = hi + lo ----------------

constexpr int POOL_ROWS = 64;

__global__ void k_pool(const ushort* __restrict__ hhi, const ushort* __restrict__ hlo,
                       const int* __restrict__ batch, float* __restrict__ g) {
    int col = threadIdx.x;  // 0..127
    int r0 = blockIdx.x * POOL_ROWS;
    int r1 = r0 + POOL_ROWS;
    if (r1 > N_NODES) r1 = N_NODES;
    if (r0 >= N_NODES) return;
    float acc = 0.f;
    int cur = batch[r0];
    int r = r0;
    for (; r + 4 <= r1; r += 4) {
        float v0 = bf2f(hhi[(size_t)r * H + col])       + bf2f(hlo[(size_t)r * H + col]);
        float v1 = bf2f(hhi[(size_t)(r + 1) * H + col]) + bf2f(hlo[(size_t)(r + 1) * H + col]);
        float v2 = bf2f(hhi[(size_t)(r + 2) * H + col]) + bf2f(hlo[(size_t)(r + 2) * H + col]);
        float v3 = bf2f(hhi[(size_t)(r + 3) * H + col]) + bf2f(hlo[(size_t)(r + 3) * H + col]);
        int b3 = batch[r + 3];
        if (b3 == cur) {
            acc += (v0 + v1) + (v2 + v3);
        } else {
            int b0 = batch[r], b1 = batch[r + 1], b2 = batch[r + 2];
            if (b0 != cur) { atomicAdd(&g[cur * H + col], acc); acc = 0.f; cur = b0; }
            acc += v0;
            if (b1 != cur) { atomicAdd(&g[cur * H + col], acc); acc = 0.f; cur = b1; }
            acc += v1;
            if (b2 != cur) { atomicAdd(&g[cur * H + col], acc); acc = 0.f; cur = b2; }
            acc += v2;
            if (b3 != cur) { atomicAdd(&g[cur * H + col], acc); acc = 0.f; cur = b3; }
            acc += v3;
        }
    }
    for (; r < r1; ++r) {
        int b = batch[r];
        if (b != cur) { atomicAdd(&g[cur * H + col], acc); acc = 0.f; cur = b; }
        acc += bf2f(hhi[(size_t)r * H + col]) + bf2f(hlo[(size_t)r * H + col]);
    }
    atomicAdd(&g[cur * H + col], acc);
}

// ---------------- MLP head ----------------

__global__ void k_mlp(const float* __restrict__ g, const float* __restrict__ W0,
                      const float* __restrict__ b0, const float* __restrict__ W1,
                      const float* __restrict__ b1, const float* __restrict__ Wh,
                      const float* __restrict__ bh, float* __restrict__ out) {
    int gi = blockIdx.x;
    int t  = threadIdx.x;  // 0..127
    __shared__ float buf0[H];
    __shared__ float buf1[H];
    __shared__ float red[2];

    float acc = b0[t];
    for (int k = 0; k < H; ++k) acc += g[gi * H + k] * W0[k * H + t];
    buf0[t] = fmaxf(acc, 0.f);
    __syncthreads();

    acc = b1[t];
    for (int k = 0; k < H; ++k) acc += buf0[k] * W1[k * H + t];
    buf1[t] = fmaxf(acc, 0.f);
    __syncthreads();

    float p = buf1[t] * Wh[t];
    for (int m = 1; m < 64; m <<= 1) p += __shfl_xor(p, m, 64);
    if ((t & 63) == 0) red[t >> 6] = p;
    __syncthreads();
    if (t == 0) out[gi] = red[0] + red[1] + bh[0];
}

// ---------------- driver ----------------

extern "C" void kernel_launch(void* const* d_in, const int* in_sizes, int n_in,
                              void* d_out, int out_size, void* d_ws, size_t ws_size,
                              hipStream_t stream) {
    const float* x     = (const float*)d_in[0];
    const int*   eic   = (const int*)d_in[1];
    const int*   eid   = (const int*)d_in[2];
    const int*   eit   = (const int*)d_in[3];
    const int*   batch = (const int*)d_in[4];
    const float* cW[5][3];
    for (int c = 0; c < 5; ++c) {
        cW[c][0] = (const float*)d_in[5 + c * 3 + 0];  // Wl
        cW[c][1] = (const float*)d_in[5 + c * 3 + 1];  // bl
        cW[c][2] = (const float*)d_in[5 + c * 3 + 2];  // Wr
    }
    const float* l0_W = (const float*)d_in[20];
    const float* l0_b = (const float*)d_in[21];
    const float* l1_W = (const float*)d_in[22];
    const float* l1_b = (const float*)d_in[23];
    const float* hd_W = (const float*)d_in[24];
    const float* hd_b = (const float*)d_in[25];
    float* outp = (float*)d_out;

    const size_t NH = (size_t)N_NODES * H;
    ushort* Ahi = (ushort*)d_ws;
    ushort* Alo = Ahi + NH;
    ushort* zb  = Alo + NH;
    ushort* yb  = zb + NH;
    ushort* Bpk = yb + NH;                     // 5 convs x 2 planes x 32768
    float*  gbuf = (float*)(Bpk + 5 * 2 * 32768);
    int* ptr_all = (int*)(gbuf + (size_t)NG * H);  // N3+1 ints (persistent)
    int* adj_all = ptr_all + (N3 + 1);             // 3*NE ints (persistent)
    // CSR-build scratch inside zb+yb (dead until first gemm, stream-ordered):
    //   bucket[NB*CAP2 int2] (64B-aligned at zb) | gcnt[NB] | rcnt[NB] | bbase[NB]
    int2* bucket = (int2*)zb;                      // 22.88 MB
    int*  gcnt   = (int*)(bucket + (size_t)NB * CAP2);
    int*  rcnt   = gcnt + NB;
    int*  bbase  = rcnt + NB;
    // total: 22.88MB + 1.7KB < zb+yb (25.6MB)

    dim3 b256(256);

    // weight pre-scatter + x split
    k_wsplit5<<<dim3(640), b256, 0, stream>>>(cW[0][0], cW[0][2], cW[1][0], cW[1][2],
                                              cW[2][0], cW[2][2], cW[3][0], cW[3][2],
                                              cW[4][0], cW[4][2], Bpk);
    k_split<<<dim3((int)(NH / 1024)), b256, 0, stream>>>(x, Ahi, Alo);

    // CSR build: bucketize -> bucket-total scan -> per-bucket ptr+scatter
    hipMemsetAsync(gcnt, 0, 2 * NB * sizeof(int), stream);  // gcnt + rcnt
    k_bucketize<<<dim3(3 * BPS), b256, 0, stream>>>(eic, eid, eit, gcnt, rcnt, bucket);
    k_btscan<<<dim3(1), b256, 0, stream>>>(rcnt, bbase, ptr_all);
    k_scatter2<<<dim3(NB), b256, 0, stream>>>(bucket, gcnt, bbase, ptr_all, adj_all);

    const int L_set[7]  = {1, 0, 0, 2, 1, 0, 0};
    const int L_conv[7] = {0, 1, 1, 2, 3, 4, 4};
    const int L_norm[7] = {1, 1, 1, 0, 1, 1, 1};

    int nWaves = (N_NODES + 1) / 2;          // 2 nodes per wave (R6-proven)
    dim3 gAgg((nWaves + 3) / 4);             // 4 waves/block
    dim3 gGemm((N_NODES + 63) / 64);         // 782

    for (int L = 0; L < 7; ++L) {
        int s = L_set[L], c = L_conv[L];
        const ushort* Bh = Bpk + (size_t)c * 65536;
        const ushort* Bl = Bh + 32768;
        k_gemm_mfma<<<gGemm, b256, 0, stream>>>(Ahi, Alo, Bh, Bl, zb, yb);
        k_aggnorm<<<gAgg, b256, 0, stream>>>(zb, yb, ptr_all + s * N_NODES, adj_all,
                                             cW[c][1], Ahi, Alo, L_norm[L]);
    }

    hipMemsetAsync(gbuf, 0, (size_t)NG * H * sizeof(float), stream);
    k_pool<<<dim3((N_NODES + POOL_ROWS - 1) / POOL_ROWS), dim3(H), 0, stream>>>(
        Ahi, Alo, batch, gbuf);
    k_mlp<<<dim3(NG), dim3(H), 0, stream>>>(gbuf, l0_W, l0_b, l1_W, l1_b, hd_W, hd_b,
                                            outp);
}